// Round 3
// baseline (147.954 us; speedup 1.0000x reference)
//
#include <hip/hip_runtime.h>

// Problem constants (fixed by the reference's setup_inputs)
#define C_DIM 64
#define P_DIM 16
#define K_DIM 9            // K1*K1
#define ZROW 10            // padded Zb row (ushorts) per (n,p): 20 B, dword-aligned
#define ZNODE (P_DIM * ZROW) // 160 ushorts = 320 B per node
#define INV2S 0.35355339059327373f  // 1/(2*sqrt(2))

typedef __attribute__((ext_vector_type(8))) short short8v;  // 8 bf16 (4 VGPRs)
typedef __attribute__((ext_vector_type(4))) float f32x4;    // MFMA accumulator

__device__ __forceinline__ ushort f2bf(float f) {
    uint u = __builtin_bit_cast(uint, f);
    return (ushort)((u + 0x7FFFu + ((u >> 16) & 1u)) >> 16);   // RNE
}
__device__ __forceinline__ float bf2f(ushort h) {
    return __builtin_bit_cast(float, ((uint)h) << 16);
}

// LDS row stride (in ushorts) for the W hi/lo tables: 72*2B = 144B rows,
// 16B aligned, bank stride 36 (=4 mod 32) -> <=2-way on b128 reads.
#define ZSTRIDE 72

// ---------------------------------------------------------------------------
// Kernel 1 (MFMA): (a) bias-init out, (b) [optional] pose -> packed-bf16,
// (c) Zb[n][p][k] = sum_c x[n,c] * W[p,k,c] via split-bf16 3-product MFMA.
// Block = 64 rows, 4 waves; wave w owns rows w*16..w*16+15, all 9 n-tiles.
// ---------------------------------------------------------------------------
__global__ __launch_bounds__(256) void z_gemm_kernel(const float* __restrict__ x,
                                                     const float* __restrict__ W,
                                                     const float* __restrict__ bias,
                                                     const float* __restrict__ pose,
                                                     float* __restrict__ out,
                                                     ushort* __restrict__ Zb,
                                                     uint* __restrict__ pose_bf,
                                                     int N) {
    __shared__ ushort w_hi[144 * ZSTRIDE];   // 20736 B
    __shared__ ushort w_lo[144 * ZSTRIDE];   // 20736 B

    const int tid = threadIdx.x;
    const int block_row = blockIdx.x * 64;

    // (a) bias-init this block's slice of out: 64 rows x 16 = 256 float4s
    {
        const float4 b4 = ((const float4*)bias)[tid & 3];
        const int o4 = block_row * 4 + tid;          // float4 index into out
        if (o4 < N * 4) ((float4*)out)[o4] = b4;
    }

    // (b) pose -> packed bf16 (only when workspace has room for the table)
    if (pose_bf != nullptr) {
        for (int i = tid; i < 64 * P_DIM; i += 256) {
            const int r = block_row + (i >> 4);
            if (r < N) {
                const float2 ab = ((const float2*)pose)[(size_t)r * P_DIM + (i & 15)];
                pose_bf[(size_t)r * P_DIM + (i & 15)] =
                    (uint)f2bf(ab.x) | ((uint)f2bf(ab.y) << 16);
            }
        }
    }

    // (c) stage W (144x64 f32) as hi/lo bf16 in LDS: 4608 float2 loads
    for (int i = tid; i < 144 * (C_DIM / 2); i += 256) {
        const int n  = i >> 5;           // W row (0..143)
        const int k2 = i & 31;           // float2 index within row
        const float2 w2 = ((const float2*)W)[i];
        const int o = n * ZSTRIDE + k2 * 2;
        const ushort h0 = f2bf(w2.x);
        const ushort h1 = f2bf(w2.y);
        w_hi[o]     = h0;
        w_hi[o + 1] = h1;
        w_lo[o]     = f2bf(w2.x - bf2f(h0));
        w_lo[o + 1] = f2bf(w2.y - bf2f(h1));
    }
    __syncthreads();

    const int lane = tid & 63;
    const int wv   = tid >> 6;    // wave -> m-subtile (16 rows)
    const int col  = lane & 15;   // A row within tile / B,C/D column
    const int kg   = lane >> 4;   // k-group 0..3

    // A operand: lane supplies x[arow][kg*8 + e (+32*chunk)], split hi/lo.
    const int arow = block_row + wv * 16 + col;
    const float* xr = x + (size_t)(arow < N ? arow : 0) * C_DIM;
    float4 x0 = ((const float4*)xr)[kg * 2];
    float4 x1 = ((const float4*)xr)[kg * 2 + 1];
    float4 x2 = ((const float4*)xr)[8 + kg * 2];
    float4 x3 = ((const float4*)xr)[8 + kg * 2 + 1];
    if (arow >= N) {
        x0 = x1 = x2 = x3 = make_float4(0.f, 0.f, 0.f, 0.f);
    }

    short8v a_hi0, a_lo0, a_hi1, a_lo1;
    {
        const float t0[8] = {x0.x, x0.y, x0.z, x0.w, x1.x, x1.y, x1.z, x1.w};
        const float t1[8] = {x2.x, x2.y, x2.z, x2.w, x3.x, x3.y, x3.z, x3.w};
        #pragma unroll
        for (int e = 0; e < 8; ++e) {
            const ushort h = f2bf(t0[e]);
            a_hi0[e] = (short)h;
            a_lo0[e] = (short)f2bf(t0[e] - bf2f(h));
            const ushort g = f2bf(t1[e]);
            a_hi1[e] = (short)g;
            a_lo1[e] = (short)f2bf(t1[e] - bf2f(g));
        }
    }

    // C/D layout (HW-verified): col = lane&15, row = kg*4 + reg
    const int orow0 = block_row + wv * 16 + kg * 4;

    #pragma unroll
    for (int nt = 0; nt < 9; ++nt) {
        const ushort* bhp = &w_hi[(nt * 16 + col) * ZSTRIDE + kg * 8];
        const ushort* blp = &w_lo[(nt * 16 + col) * ZSTRIDE + kg * 8];
        const short8v bh0 = *(const short8v*)bhp;          // k chunk 0
        const short8v bh1 = *(const short8v*)(bhp + 32);   // k chunk 1
        const short8v bl0 = *(const short8v*)blp;
        const short8v bl1 = *(const short8v*)(blp + 32);

        f32x4 acc = {0.f, 0.f, 0.f, 0.f};
        // split-bf16 3-product: lo terms first, hi*hi last
        acc = __builtin_amdgcn_mfma_f32_16x16x32_bf16(a_lo0, bh0, acc, 0, 0, 0);
        acc = __builtin_amdgcn_mfma_f32_16x16x32_bf16(a_hi0, bl0, acc, 0, 0, 0);
        acc = __builtin_amdgcn_mfma_f32_16x16x32_bf16(a_lo1, bh1, acc, 0, 0, 0);
        acc = __builtin_amdgcn_mfma_f32_16x16x32_bf16(a_hi1, bl1, acc, 0, 0, 0);
        acc = __builtin_amdgcn_mfma_f32_16x16x32_bf16(a_hi0, bh0, acc, 0, 0, 0);
        acc = __builtin_amdgcn_mfma_f32_16x16x32_bf16(a_hi1, bh1, acc, 0, 0, 0);

        // padded-layout store index: j = p*9+k  ->  (j/9)*10 + j%9
        const int j  = nt * 16 + col;
        const int zi = (j / 9) * ZROW + (j % 9);
        #pragma unroll
        for (int r = 0; r < 4; ++r) {
            const int row = orow0 + r;
            if (row < N) Zb[(size_t)row * ZNODE + zi] = f2bf(acc[r]);
        }
    }
}

// ---------------------------------------------------------------------------
// Kernel 2: edge messages + scatter-add (unsorted).
// thread-slot = (eg, p); 16 lanes share an edge; 8 edges per slot.
// Zb rows are loaded EAGERLY (whole 9-value row as 5 dwords, address depends
// only on c) so the gather chain is ei -> {pos, pose, Zb} -> compute -> atomic
// (2 serial miss levels instead of 3). Tap selection happens in-register:
// the 4 spline taps are always e(b), e(b+1), e(b+3), e(b+4), b = b0 + 3*b1.
// ---------------------------------------------------------------------------
#define EILP 8
template <bool USEBF>
__global__ __launch_bounds__(256) void edge_kernel(const int* __restrict__ ei,
                                                   const float* __restrict__ pos,
                                                   const float* __restrict__ pose,
                                                   const uint* __restrict__ pose_bf,
                                                   const ushort* __restrict__ Zb,
                                                   float* __restrict__ out,
                                                   int E) {
    const int p  = threadIdx.x & 15;
    const int eg = threadIdx.x >> 4;
    const int e0 = blockIdx.x * (16 * EILP) + eg;

    int  r[EILP], c[EILP];
    bool valid[EILP];
    #pragma unroll
    for (int it = 0; it < EILP; ++it) {
        int e = e0 + it * 16;
        valid[it] = (e < E);
        int ec = valid[it] ? e : 0;
        r[it] = ei[ec];
        c[it] = ei[E + ec];
    }

    // --- eager independent gathers: pos, pose, and the full Zb row ---
    float d0[EILP], d1[EILP];
    #pragma unroll
    for (int it = 0; it < EILP; ++it) {
        const float2 pc = ((const float2*)pos)[c[it]];
        const float2 pr = ((const float2*)pos)[r[it]];
        d0[it] = (pc.x - pr.x) * INV2S;
        d1[it] = (pc.y - pr.y) * INV2S;
    }

    float a_[EILP], b_[EILP];
    #pragma unroll
    for (int it = 0; it < EILP; ++it) {
        if (USEBF) {
            const uint ab = pose_bf[(size_t)r[it] * P_DIM + p];
            a_[it] = bf2f((ushort)(ab & 0xffffu));
            b_[it] = bf2f((ushort)(ab >> 16));
        } else {
            const float2 ab = ((const float2*)pose)[(size_t)r[it] * P_DIM + p];
            a_[it] = ab.x;
            b_[it] = ab.y;
        }
    }

    uint q0[EILP], q1[EILP], q2[EILP], q3[EILP], q4[EILP];
    #pragma unroll
    for (int it = 0; it < EILP; ++it) {
        const uint* Zp = (const uint*)(Zb + (size_t)c[it] * ZNODE) + p * (ZROW / 2);
        q0[it] = Zp[0];
        q1[it] = Zp[1];
        q2[it] = Zp[2];
        q3[it] = Zp[3];
        q4[it] = Zp[4];
    }

    #pragma unroll
    for (int it = 0; it < EILP; ++it) {
        const float p0 = fmaf(a_[it], d0[it], fmaf(-b_[it], d1[it], 0.5f));
        const float p1 = fmaf(b_[it], d0[it], fmaf( a_[it], d1[it], 0.5f));

        const float v0 = fminf(fmaxf(p0, 0.0f), 1.0f) * 2.0f;
        const float v1 = fminf(fmaxf(p1, 0.0f), 1.0f) * 2.0f;
        // window base: b0 = (v0>=1), b1 = (v1>=1); fracs relative to base.
        // (at v==2 the base is 1, frac==1 -> weight lands on column 2; matches
        //  the reference's clamped i00==i01==2 case exactly)
        const bool b0 = (v0 >= 1.0f);
        const bool b1 = (v1 >= 1.0f);
        const float f0 = v0 - (b0 ? 1.0f : 0.0f);
        const float f1 = v1 - (b1 ? 1.0f : 0.0f);

        // 6-element window w0..w5 = e(3*b1) .. e(3*b1+5) as 3 dwords
        const uint A0 = q0[it], A1 = q1[it], A2 = q2[it], A3 = q3[it], A4 = q4[it];
        const uint W0 = b1 ? ((A1 >> 16) | (A2 << 16)) : A0;
        const uint W1 = b1 ? ((A2 >> 16) | (A3 << 16)) : A1;
        const uint W2 = b1 ? ((A3 >> 16) | (A4 << 16)) : A2;
        // taps: z00=w(b0), z10=w(b0+1), z01=w(b0+3), z11=w(b0+4)
        const uint s = b0 ? 16u : 0u;
        const float z00 = bf2f((ushort)(W0 >> s));
        const float z10 = bf2f((ushort)(b0 ? (W1 & 0xffffu) : (W0 >> 16)));
        const float z01 = bf2f((ushort)(b0 ? (W2 & 0xffffu) : (W1 >> 16)));
        const float z11 = bf2f((ushort)(W2 >> s));

        const float w00 = (1.0f - f0) * (1.0f - f1);
        const float w01 = (1.0f - f0) * f1;
        const float w10 = f0 * (1.0f - f1);
        const float w11 = f0 * f1;

        float m = w00 * z00;
        m = fmaf(w01, z01, m);
        m = fmaf(w10, z10, m);
        m = fmaf(w11, z11, m);

        if (valid[it]) atomicAdd(&out[(size_t)r[it] * P_DIM + p], m);
    }
}

// ---------------------------------------------------------------------------
extern "C" void kernel_launch(void* const* d_in, const int* in_sizes, int n_in,
                              void* d_out, int out_size, void* d_ws, size_t ws_size,
                              hipStream_t stream) {
    const float* x    = (const float*)d_in[0];
    const float* pos  = (const float*)d_in[1];
    const float* pose = (const float*)d_in[2];
    const float* W    = (const float*)d_in[3];
    const float* bias = (const float*)d_in[4];
    const int*   ei   = (const int*)d_in[5];

    const int N = in_sizes[0] / C_DIM;   // 50000
    const int E = in_sizes[5] / 2;       // 800000

    float* out = (float*)d_out;
    ushort* Zb = (ushort*)d_ws;          // N*160 bf16 = 16.0 MB (padded rows)

    // pose-bf16 table only if the workspace actually has room for it
    const size_t zb_bytes   = (size_t)N * ZNODE * sizeof(ushort);
    const size_t pose_bytes = (size_t)N * P_DIM * sizeof(uint);
    uint* pose_bf = (ws_size >= zb_bytes + pose_bytes)
                        ? (uint*)((char*)d_ws + zb_bytes) : nullptr;

    z_gemm_kernel<<<(N + 63) / 64, 256, 0, stream>>>(x, W, bias, pose, out, Zb, pose_bf, N);

    const int eblocks = (E + 16 * EILP - 1) / (16 * EILP);
    if (pose_bf != nullptr)
        edge_kernel<true><<<eblocks, 256, 0, stream>>>(ei, pos, pose, pose_bf, Zb, out, E);
    else
        edge_kernel<false><<<eblocks, 256, 0, stream>>>(ei, pos, pose, pose_bf, Zb, out, E);
}